// Round 7
// baseline (271.593 us; speedup 1.0000x reference)
//
#include <hip/hip_runtime.h>

// Problem constants (fixed by setup_inputs)
#define B_    8
#define D_    4
#define H_    640
#define W_    640
#define HW_   (H_ * W_)      // 409600
#define L_    8
#define NL    (L_ - 1)       // labels 1..7
#define BLOCK 256
#define VITER 4              // float4 iterations per thread -> 16 px/thread
#define PXB   (BLOCK * 4 * VITER)           // 4096 px per block
#define GRIDX (HW_ / PXB)                   // 100 -> grid (100,8) = 800 blocks
#define NBLK  (GRIDX * B_)                  // 800

__device__ __forceinline__ void gatom_add(float* p, float v) {
    unsafeAtomicAdd(p, v);   // global_atomic_add_f32
}

// ---------------------------------------------------------------------------
// ws layout (4-byte elements):
//   int   firstIdx [64] @0     int secondIdx[64] @64
//   int   cntf_i   [64] @128   int cntk_i   [64] @192
//   float sumemb  [256] @256   float sumvalb [8] @512
//   int   bar       [1] @520   (grid barrier arrival counter)
// ---------------------------------------------------------------------------
__global__ void k_init(int* ib) {
    int t = threadIdx.x;
    if (t < 128) ib[t] = HW_;        // firstIdx + secondIdx
    ib[128 + t] = 0;                 // 128..383
    if (t < 137) ib[384 + t] = 0;    // 384..520 (sums, sumvalb, bar)
}

// ---------------------------------------------------------------------------
// Fused kernel. Phase 1: per-label counts / kernel-region sums / first+second
// occurrence (bit-plane masks + predicated FMAs, all 28 vector loads issued
// up front). Grid barrier (all 800 blocks co-resident: 4 waves/EU bound ->
// >=1024-block capacity). Phase 2: l_agg from the emb values STILL IN
// REGISTERS — no second pass over memory.
// ---------------------------------------------------------------------------
__global__ __launch_bounds__(BLOCK, 4) void k_fused(
        const float* __restrict__ emb, const int* __restrict__ inst,
        const float* __restrict__ kern, const float* __restrict__ tmask,
        int* __restrict__ firstIdx, int* __restrict__ secondIdx,
        int* __restrict__ cntf_i, int* __restrict__ cntk_i,
        float* __restrict__ sumemb, float* __restrict__ sumvalb,
        int* __restrict__ bar) {
    __shared__ int    sCnt[L_];       // cf<<16 | ck
    __shared__ float  sSum[L_ * D_];
    __shared__ int    sM1[L_], sM2[L_];
    __shared__ float4 sMean[L_];
    __shared__ float  sCd[L_], sInv[L_];
    __shared__ float  sAcc;

    const int tid  = threadIdx.x;
    const int lane = tid & 63;
    if (tid < L_) { sCnt[tid] = 0; sM1[tid] = HW_; sM2[tid] = HW_; }
    if (tid < L_ * D_) sSum[tid] = 0.f;
    if (tid == 0) sAcc = 0.f;
    __syncthreads();

    const int b = blockIdx.y;
    const int blockbase = blockIdx.x * PXB;
    const float* embb = emb + (size_t)b * D_ * HW_;
    const int base = b * HW_;
    const int o0 = blockbase + tid * 4;

    // ---- issue ALL loads up front (12 label-stream + 16 emb vec4) ----
    int4 LB[VITER]; float4 TM[VITER], KN[VITER];
    #pragma unroll
    for (int it = 0; it < VITER; ++it) {
        const int off = o0 + it * (BLOCK * 4);
        LB[it] = *(const int4*)  (inst  + base + off);
        TM[it] = *(const float4*)(tmask + base + off);
        KN[it] = *(const float4*)(kern  + base + off);
    }
    float4 E[VITER][D_];
    #pragma unroll
    for (int it = 0; it < VITER; ++it)
        #pragma unroll
        for (int d = 0; d < D_; ++d)
            E[it][d] = *(const float4*)(embb + d * HW_ + o0 + it * (BLOCK * 4));

    // ---- masks + packed labels (consumes label streams) ----
    unsigned long long lp = 0;            // 4-bit label per px (tmask-filtered)
    int bp0 = 0, bp1 = 0, bp2 = 0, km = 0;
    #pragma unroll
    for (int it = 0; it < VITER; ++it) {
        const int*   labA = (const int*)&LB[it];
        const float* tmA  = (const float*)&TM[it];
        const float* knA  = (const float*)&KN[it];
        #pragma unroll
        for (int c = 0; c < 4; ++c) {
            const int px = it * 4 + c;
            const int lf  = (tmA[c] > 0.5f) ? labA[c] : 0;
            const bool kb = (knA[c] > 0.5f);
            bp0 |= (lf & 1) << px;
            bp1 |= ((lf >> 1) & 1) << px;
            bp2 |= ((lf >> 2) & 1) << px;
            km  |= (kb ? 1 : 0) << px;
            lp  |= (unsigned long long)lf << (4 * px);
        }
    }

    // ---- kernel-region embedding sums (predicated FMAs on register emb) ----
    float sm[NL][D_];
    #pragma unroll
    for (int l = 0; l < NL; ++l)
        #pragma unroll
        for (int d = 0; d < D_; ++d) sm[l][d] = 0.f;
    #pragma unroll
    for (int it = 0; it < VITER; ++it) {
        const float* e0A = (const float*)&E[it][0];
        const float* e1A = (const float*)&E[it][1];
        const float* e2A = (const float*)&E[it][2];
        const float* e3A = (const float*)&E[it][3];
        #pragma unroll
        for (int c = 0; c < 4; ++c) {
            const int px = it * 4 + c;
            const int lf = (int)((lp >> (4 * px)) & 7);
            const int lfk = ((km >> px) & 1) ? lf : 0;
            #pragma unroll
            for (int l = 1; l < L_; ++l) {
                const float mk = (lfk == l) ? 1.0f : 0.0f;
                sm[l - 1][0] += mk * e0A[c];
                sm[l - 1][1] += mk * e1A[c];
                sm[l - 1][2] += mk * e2A[c];
                sm[l - 1][3] += mk * e3A[c];
            }
        }
    }

    // ---- per-thread counts + first/second from bit-planes ----
    const int nb0 = ~bp0, nb1 = ~bp1, nb2 = ~bp2;
    int cnt[NL], m1[NL], m2[NL];
    #pragma unroll
    for (int l = 1; l < L_; ++l) {
        const int k = l - 1;
        int h = ((l & 1) ? bp0 : nb0) & ((l & 2) ? bp1 : nb1) & ((l & 4) ? bp2 : nb2);
        h &= 0xFFFF;
        cnt[k] = (__popc(h) << 16) | __popc(h & km);
        const int h2 = h & (h - 1);
        const int p1 = __ffs(h) - 1;      // valid only if h
        const int p2 = __ffs(h2) - 1;
        // px -> pixel index: o0 + (px>>2)*BLOCK*4 + (px&3), monotone in px
        m1[k] = h  ? (o0 + (p1 >> 2) * (BLOCK * 4) + (p1 & 3)) : HW_;
        m2[k] = h2 ? (o0 + (p2 >> 2) * (BLOCK * 4) + (p2 & 3)) : HW_;
    }

    // ---- 64-lane butterfly (49 values, valid at lane 0) ----
    #pragma unroll
    for (int l = 0; l < NL; ++l) {
        #pragma unroll
        for (int off = 32; off > 0; off >>= 1) {
            cnt[l]   += __shfl_down(cnt[l], off);
            sm[l][0] += __shfl_down(sm[l][0], off);
            sm[l][1] += __shfl_down(sm[l][1], off);
            sm[l][2] += __shfl_down(sm[l][2], off);
            sm[l][3] += __shfl_down(sm[l][3], off);
            int o1 = __shfl_down(m1[l], off);
            int o2 = __shfl_down(m2[l], off);
            m2[l] = min(min(m2[l], o2), max(m1[l], o1));   // two-min combine
            m1[l] = min(m1[l], o1);
        }
    }
    if (lane == 0) {
        #pragma unroll
        for (int l = 0; l < NL; ++l) {
            atomicAdd(&sCnt[l + 1], cnt[l]);   // fields <= 4096, no overflow
            #pragma unroll
            for (int d = 0; d < D_; ++d) atomicAdd(&sSum[(l + 1) * D_ + d], sm[l][d]);
            int old = atomicMin(&sM1[l + 1], m1[l]);
            atomicMin(&sM2[l + 1], max(old, m1[l]));
            atomicMin(&sM2[l + 1], m2[l]);
        }
    }
    __syncthreads();

    // ---- global atomics ----
    if (tid >= 1 && tid < L_) {
        const int pc = sCnt[tid];
        atomicAdd(&cntf_i[b * L_ + tid], pc >> 16);
        atomicAdd(&cntk_i[b * L_ + tid], pc & 0xFFFF);
        int old = atomicMin(&firstIdx[b * L_ + tid], sM1[tid]);
        atomicMin(&secondIdx[b * L_ + tid], max(old, sM1[tid]));
        atomicMin(&secondIdx[b * L_ + tid], sM2[tid]);
    }
    if (tid >= D_ && tid < L_ * D_)
        gatom_add(&sumemb[b * L_ * D_ + tid], sSum[tid]);

    // ---- grid barrier (all NBLK blocks co-resident by capacity math) ----
    __syncthreads();                       // drains this block's vmem ops
    if (tid == 0) {
        __threadfence();
        atomicAdd(bar, 1);
        while (__hip_atomic_load(bar, __ATOMIC_RELAXED,
                                 __HIP_MEMORY_SCOPE_AGENT) < NBLK)
            __builtin_amdgcn_s_sleep(8);
        __threadfence();
    }
    __syncthreads();

    // ---- phase 2 setup: coherent (agent-scope) reads of the global stats ----
    if (tid >= 1 && tid < L_) {
        const int gi = b * L_ + tid;
        const float ckv = (float)__hip_atomic_load(&cntk_i[gi], __ATOMIC_RELAXED, __HIP_MEMORY_SCOPE_AGENT);
        const float cfv = (float)__hip_atomic_load(&cntf_i[gi], __ATOMIC_RELAXED, __HIP_MEMORY_SCOPE_AGENT);
        const int   f   = min(__hip_atomic_load(&firstIdx[gi],  __ATOMIC_RELAXED, __HIP_MEMORY_SCOPE_AGENT), HW_ - 1);
        const int   s   = min(__hip_atomic_load(&secondIdx[gi], __ATOMIC_RELAXED, __HIP_MEMORY_SCOPE_AGENT), HW_ - 1);
        const float invk = 1.0f / fmaxf(ckv, 1.0f);
        float4 mu;
        mu.x = __hip_atomic_load(&sumemb[gi * D_ + 0], __ATOMIC_RELAXED, __HIP_MEMORY_SCOPE_AGENT) * invk;
        mu.y = __hip_atomic_load(&sumemb[gi * D_ + 1], __ATOMIC_RELAXED, __HIP_MEMORY_SCOPE_AGENT) * invk;
        mu.z = __hip_atomic_load(&sumemb[gi * D_ + 2], __ATOMIC_RELAXED, __HIP_MEMORY_SCOPE_AGENT) * invk;
        mu.w = __hip_atomic_load(&sumemb[gi * D_ + 3], __ATOMIC_RELAXED, __HIP_MEMORY_SCOPE_AGENT) * invk;
        const float diag = sqrtf((float)(H_ * H_ + W_ * W_));
        const float r0 = (float)(f / W_), c0 = (float)(f % W_);
        const float r1 = (float)(s / W_), c1 = (float)(s % W_);
        sMean[tid] = mu;
        sCd[tid]  = __expf(sqrtf((r0 - c0) * (r0 - c0) + (r1 - c1) * (r1 - c1))
                           / diag * 0.5f);
        sInv[tid] = 1.0f / fmaxf(cfv, 1.0f);
    }
    if (tid == 0) {
        sMean[0] = make_float4(0.f, 0.f, 0.f, 0.f);
        sCd[0] = 0.f; sInv[0] = 0.f;
    }
    __syncthreads();

    // ---- phase 2: l_agg from register-resident emb ----
    float acc = 0.f;
    #pragma unroll
    for (int it = 0; it < VITER; ++it) {
        const float* e0A = (const float*)&E[it][0];
        const float* e1A = (const float*)&E[it][1];
        const float* e2A = (const float*)&E[it][2];
        const float* e3A = (const float*)&E[it][3];
        #pragma unroll
        for (int c = 0; c < 4; ++c) {
            const int px = it * 4 + c;
            const int lf = (int)((lp >> (4 * px)) & 7);
            const float4 mu = sMean[lf];     // 8 float4 = 32 banks: conflict-free
            float dx = e0A[c] - mu.x, dy = e1A[c] - mu.y;
            float dz = e2A[c] - mu.z, dw = e3A[c] - mu.w;
            float d2 = dx * dx + dy * dy + dz * dz + dw * dw;
            float x  = fmaxf(sCd[lf] * sqrtf(d2) - 0.5f, 0.0f);  // lf==0 -> 0
            acc += __logf(x * x + 1.0f) * sInv[lf];
        }
    }
    #pragma unroll
    for (int off = 32; off > 0; off >>= 1)
        acc += __shfl_down(acc, off);
    if (lane == 0) atomicAdd(&sAcc, acc);
    __syncthreads();
    if (tid == 0) gatom_add(&sumvalb[b], sAcc);
}

// ---------------------------------------------------------------------------
// k_final: parallel epilogue — one thread per (b, i, j) term.
// ---------------------------------------------------------------------------
__global__ __launch_bounds__(512) void k_final(
        const int* __restrict__ firstIdx, const int* __restrict__ secondIdx,
        const int* __restrict__ cntk_i, const float* __restrict__ sumemb,
        const float* __restrict__ sumvalb, float* __restrict__ out) {
    __shared__ float sWave[8];
    const int tid = threadIdx.x;
    const int b = tid >> 6, ij = tid & 63, i = ij >> 3, j = ij & 7;
    const float diag = sqrtf((float)(H_ * H_ + W_ * W_));

    float mi[D_], mj[D_];
    {
        float ci = 1.0f / fmaxf((float)cntk_i[b * L_ + i], 1.0f);
        float cj = 1.0f / fmaxf((float)cntk_i[b * L_ + j], 1.0f);
        #pragma unroll
        for (int d = 0; d < D_; ++d) {
            mi[d] = (i > 0) ? sumemb[(b * L_ + i) * D_ + d] * ci : 0.0f;
            mj[d] = (j > 0) ? sumemb[(b * L_ + j) * D_ + d] * cj : 0.0f;
        }
    }

    float contrib = 0.0f;
    if (j == 0) {            // l_reg term for label i (i=0 gives 0)
        float d2 = 0.f;
        #pragma unroll
        for (int d = 0; d < D_; ++d) d2 += mi[d] * mi[d];
        float n = (d2 > 0.f) ? sqrtf(d2) : 0.f;
        contrib += __logf(n + 1.0f) * (0.001f / (float)L_);
    }
    if (i == 0 && j == 1)    // l_agg (already /cntf per label)
        contrib += sumvalb[b] * (1.0f / (float)NL);
    if (i >= 1 && j >= 1 && i != j) {   // l_dis pair term
        float d2 = 0.f;
        #pragma unroll
        for (int d = 0; d < D_; ++d) {
            float df = mi[d] - mj[d];
            d2 += df * df;
        }
        float Dn = (d2 > 0.f) ? sqrtf(d2) : 0.f;
        int fi = min(firstIdx[b * L_ + i],  HW_ - 1);
        int si = min(secondIdx[b * L_ + i], HW_ - 1);
        int fj = min(firstIdx[b * L_ + j],  HW_ - 1);
        int sj = min(secondIdx[b * L_ + j], HW_ - 1);
        float ssi = (float)(fi / W_) + (float)(fi % W_);
        float tti = (float)(si / W_) + (float)(si % W_);
        float ssj = (float)(fj / W_) + (float)(fj % W_);
        float ttj = (float)(sj / W_) + (float)(sj % W_);
        float dx = ssi - ssj, dy = tti - ttj;
        float dp = sqrtf(dx * dx + dy * dy);
        float coef = 1.0f - 20.0f * __expf(-4.0f - 2.5f * dp / diag);
        float x = fmaxf(3.0f - coef * Dn, 0.0f);   // 2*delta_d = 3.0
        contrib += __logf(x * x + 1.0f) * (1.0f / 42.0f);
    }

    #pragma unroll
    for (int off = 32; off > 0; off >>= 1)
        contrib += __shfl_down(contrib, off);
    if ((tid & 63) == 0) sWave[tid >> 6] = contrib;
    __syncthreads();
    if (tid == 0) {
        float t = 0.f;
        #pragma unroll
        for (int w = 0; w < 8; ++w) t += sWave[w];
        out[0] = t * (1.0f / (float)B_);           // LOSS_WEIGHT = 1
    }
}

extern "C" void kernel_launch(void* const* d_in, const int* in_sizes, int n_in,
                              void* d_out, int out_size, void* d_ws, size_t ws_size,
                              hipStream_t stream) {
    const float* emb   = (const float*)d_in[0];
    const int*   inst  = (const int*)  d_in[1];
    const float* kern  = (const float*)d_in[2];
    const float* tmask = (const float*)d_in[3];
    // d_in[4] = bboxes, unused by the reference

    int*   ib        = (int*)d_ws;
    int*   firstIdx  = ib;
    int*   secondIdx = ib + 64;
    int*   cntf_i    = ib + 128;
    int*   cntk_i    = ib + 192;
    float* sumemb    = (float*)(ib + 256);
    float* sumvalb   = (float*)(ib + 512);
    int*   bar       = ib + 520;
    float* out       = (float*)d_out;

    dim3 grid(GRIDX, B_);   // (100, 8) = 800 blocks, all co-resident

    k_init <<<1, 256, 0, stream>>>(ib);
    k_fused<<<grid, BLOCK, 0, stream>>>(emb, inst, kern, tmask,
                                        firstIdx, secondIdx, cntf_i, cntk_i,
                                        sumemb, sumvalb, bar);
    k_final<<<1, 512, 0, stream>>>(firstIdx, secondIdx, cntk_i,
                                   sumemb, sumvalb, out);
}

// Round 8
// 149.873 us; speedup vs baseline: 1.8122x; 1.8122x over previous
//
#include <hip/hip_runtime.h>

// Problem constants (fixed by setup_inputs)
#define B_    8
#define D_    4
#define H_    640
#define W_    640
#define HW_   (H_ * W_)      // 409600
#define L_    8
#define NL    (L_ - 1)       // labels 1..7
#define BLOCK 256
#define VITER 4              // float4 iterations per thread -> 16 px/thread
#define PXB   (BLOCK * 4 * VITER)           // 4096 px per block
#define GRIDX (HW_ / PXB)                   // 100 -> grid (100,8) = 800 blocks

__device__ __forceinline__ void gatom_add(float* p, float v) {
    unsafeAtomicAdd(p, v);   // global_atomic_add_f32
}

// ---------------------------------------------------------------------------
// ws layout (4-byte elements):
//   int   firstIdx [64] @0     int secondIdx[64] @64
//   int   cntf_i   [64] @128   int cntk_i   [64] @192
//   float sumemb  [256] @256   float sumvalb [8] @512
//   uint2 lblpack  [204800] @1024  (16 x 4-bit labels per thread)
// ---------------------------------------------------------------------------
__global__ void k_init(int* ib) {
    int t = threadIdx.x;
    if (t < 128) ib[t] = HW_;        // firstIdx + secondIdx
    ib[128 + t] = 0;                 // 128..383
    if (t < 137) ib[384 + t] = 0;    // 384..520
}

// ---------------------------------------------------------------------------
// K1: counts, kernel-region sums, first+second occurrence, label export.
//  - waves_per_eu pinned to 4 (grid supplies only 3.125/EU): VGPR budget 128,
//    compiler cannot register-starve for phantom occupancy (R7 lesson)
//  - double-buffered load slots: it+1's 7 vec4 loads in flight during it's
//    compute (real software pipeline)
//  - bit-plane masks for counts/first/second (cheap post-processing), packed
//    4-bit labels exported for pass3
// ---------------------------------------------------------------------------
__global__ __attribute__((amdgpu_flat_work_group_size(BLOCK, BLOCK),
                          amdgpu_waves_per_eu(4, 4)))
void k_pass1(
        const float* __restrict__ emb, const int* __restrict__ inst,
        const float* __restrict__ kern, const float* __restrict__ tmask,
        int* __restrict__ firstIdx, int* __restrict__ secondIdx,
        int* __restrict__ cntf_i, int* __restrict__ cntk_i,
        float* __restrict__ sumemb, uint2* __restrict__ lblpack) {
    __shared__ int   sCnt[L_];       // cf<<16 | ck
    __shared__ float sSum[L_ * D_];
    __shared__ int   sM1[L_], sM2[L_];

    const int tid  = threadIdx.x;
    const int lane = tid & 63;
    if (tid < L_) { sCnt[tid] = 0; sM1[tid] = HW_; sM2[tid] = HW_; }
    if (tid < L_ * D_) sSum[tid] = 0.f;
    __syncthreads();

    const int b = blockIdx.y;
    const int blockbase = blockIdx.x * PXB;
    const float* embb = emb + (size_t)b * D_ * HW_;
    const int base = b * HW_;
    const int o0 = blockbase + tid * 4;

    // double-buffered load slots
    int4 LB[2]; float4 TM[2], KN[2], E0[2], E1[2], E2[2], E3[2];
    {   // preload it = 0
        LB[0] = *(const int4*)  (inst  + base + o0);
        TM[0] = *(const float4*)(tmask + base + o0);
        KN[0] = *(const float4*)(kern  + base + o0);
        E0[0] = *(const float4*)(embb + 0 * HW_ + o0);
        E1[0] = *(const float4*)(embb + 1 * HW_ + o0);
        E2[0] = *(const float4*)(embb + 2 * HW_ + o0);
        E3[0] = *(const float4*)(embb + 3 * HW_ + o0);
    }

    float sm[NL][D_];
    #pragma unroll
    for (int l = 0; l < NL; ++l)
        #pragma unroll
        for (int d = 0; d < D_; ++d) sm[l][d] = 0.f;
    int bp0 = 0, bp1 = 0, bp2 = 0, km = 0;
    unsigned int lpLo = 0, lpHi = 0;

    #pragma unroll
    for (int it = 0; it < VITER; ++it) {
        const int cur = it & 1, nxt = cur ^ 1;
        if (it + 1 < VITER) {        // prefetch next iteration's 7 vectors
            const int o = o0 + (it + 1) * (BLOCK * 4);
            LB[nxt] = *(const int4*)  (inst  + base + o);
            TM[nxt] = *(const float4*)(tmask + base + o);
            KN[nxt] = *(const float4*)(kern  + base + o);
            E0[nxt] = *(const float4*)(embb + 0 * HW_ + o);
            E1[nxt] = *(const float4*)(embb + 1 * HW_ + o);
            E2[nxt] = *(const float4*)(embb + 2 * HW_ + o);
            E3[nxt] = *(const float4*)(embb + 3 * HW_ + o);
        }
        const int*   labA = (const int*)&LB[cur];
        const float* tmA  = (const float*)&TM[cur];
        const float* knA  = (const float*)&KN[cur];
        const float* e0A  = (const float*)&E0[cur];
        const float* e1A  = (const float*)&E1[cur];
        const float* e2A  = (const float*)&E2[cur];
        const float* e3A  = (const float*)&E3[cur];

        #pragma unroll
        for (int c = 0; c < 4; ++c) {
            const int px = it * 4 + c;               // compile-time
            const int lf  = (tmA[c] > 0.5f) ? labA[c] : 0;
            const bool kb = (knA[c] > 0.5f);
            const int lfk = kb ? lf : 0;
            bp0 |= (lf & 1) << px;
            bp1 |= ((lf >> 1) & 1) << px;
            bp2 |= ((lf >> 2) & 1) << px;
            km  |= (kb ? 1 : 0) << px;
            if (px < 8) lpLo |= (unsigned int)lf << (4 * px);
            else        lpHi |= (unsigned int)lf << (4 * (px - 8));
            #pragma unroll
            for (int l = 1; l < L_; ++l) {
                const float mk = (lfk == l) ? 1.0f : 0.0f;
                sm[l - 1][0] += mk * e0A[c];
                sm[l - 1][1] += mk * e1A[c];
                sm[l - 1][2] += mk * e2A[c];
                sm[l - 1][3] += mk * e3A[c];
            }
        }
    }

    // export packed labels for pass3 (same thread/block mapping there)
    lblpack[(size_t)(b * GRIDX + blockIdx.x) * BLOCK + tid] = make_uint2(lpLo, lpHi);

    // ---- per-thread counts + first/second from bit-planes ----
    const int nb0 = ~bp0, nb1 = ~bp1, nb2 = ~bp2;
    int cnt[NL], m1[NL], m2[NL];
    #pragma unroll
    for (int l = 1; l < L_; ++l) {
        const int k = l - 1;
        int h = ((l & 1) ? bp0 : nb0) & ((l & 2) ? bp1 : nb1) & ((l & 4) ? bp2 : nb2);
        h &= 0xFFFF;
        cnt[k] = (__popc(h) << 16) | __popc(h & km);
        const int h2 = h & (h - 1);
        const int p1 = __ffs(h) - 1;      // valid only if h
        const int p2 = __ffs(h2) - 1;
        // px -> pixel index: o0 + (px>>2)*BLOCK*4 + (px&3), monotone in px
        m1[k] = h  ? (o0 + (p1 >> 2) * (BLOCK * 4) + (p1 & 3)) : HW_;
        m2[k] = h2 ? (o0 + (p2 >> 2) * (BLOCK * 4) + (p2 & 3)) : HW_;
    }

    // ---- 64-lane butterfly (49 values, valid at lane 0) ----
    #pragma unroll
    for (int l = 0; l < NL; ++l) {
        #pragma unroll
        for (int off = 32; off > 0; off >>= 1) {
            cnt[l]   += __shfl_down(cnt[l], off);
            sm[l][0] += __shfl_down(sm[l][0], off);
            sm[l][1] += __shfl_down(sm[l][1], off);
            sm[l][2] += __shfl_down(sm[l][2], off);
            sm[l][3] += __shfl_down(sm[l][3], off);
            int o1 = __shfl_down(m1[l], off);
            int o2 = __shfl_down(m2[l], off);
            m2[l] = min(min(m2[l], o2), max(m1[l], o1));   // two-min combine
            m1[l] = min(m1[l], o1);
        }
    }
    if (lane == 0) {
        #pragma unroll
        for (int l = 0; l < NL; ++l) {
            atomicAdd(&sCnt[l + 1], cnt[l]);   // fields <= 4096, no overflow
            #pragma unroll
            for (int d = 0; d < D_; ++d) atomicAdd(&sSum[(l + 1) * D_ + d], sm[l][d]);
            int old = atomicMin(&sM1[l + 1], m1[l]);
            atomicMin(&sM2[l + 1], max(old, m1[l]));
            atomicMin(&sM2[l + 1], m2[l]);
        }
    }
    __syncthreads();

    if (tid >= 1 && tid < L_) {
        const int pc = sCnt[tid];
        atomicAdd(&cntf_i[b * L_ + tid], pc >> 16);
        atomicAdd(&cntk_i[b * L_ + tid], pc & 0xFFFF);
        int old = atomicMin(&firstIdx[b * L_ + tid], sM1[tid]);
        atomicMin(&secondIdx[b * L_ + tid], max(old, sM1[tid]));
        atomicMin(&secondIdx[b * L_ + tid], sM2[tid]);
    }
    if (tid >= D_ && tid < L_ * D_)
        gatom_add(&sumemb[b * L_ * D_ + tid], sSum[tid]);
}

// ---------------------------------------------------------------------------
// K3: l_agg — reads emb + packed labels only (~54 MB vs 78.6 MB); all 17
// loads issued up front under the pinned register budget; single scalar
// accumulator (val * 1/cntf[lf]).
// ---------------------------------------------------------------------------
__global__ __attribute__((amdgpu_flat_work_group_size(BLOCK, BLOCK),
                          amdgpu_waves_per_eu(4, 4)))
void k_pass3(
        const float* __restrict__ emb, const uint2* __restrict__ lblpack,
        const int* __restrict__ firstIdx, const int* __restrict__ secondIdx,
        const int* __restrict__ cntk_i, const int* __restrict__ cntf_i,
        const float* __restrict__ sumemb, float* __restrict__ sumvalb) {
    __shared__ float4 sMean[L_];
    __shared__ float  sCd[L_], sInv[L_];
    __shared__ float  sAcc;

    const int tid = threadIdx.x;
    const int b   = blockIdx.y;

    if (tid < L_) {
        float4 mu = {0.f, 0.f, 0.f, 0.f};
        float cd = 0.f, inv = 0.f;
        if (tid > 0) {
            const float invk = 1.0f / fmaxf((float)cntk_i[b * L_ + tid], 1.0f);
            mu.x = sumemb[b * L_ * D_ + tid * D_ + 0] * invk;
            mu.y = sumemb[b * L_ * D_ + tid * D_ + 1] * invk;
            mu.z = sumemb[b * L_ * D_ + tid * D_ + 2] * invk;
            mu.w = sumemb[b * L_ * D_ + tid * D_ + 3] * invk;
            const float diag = sqrtf((float)(H_ * H_ + W_ * W_));
            int f = min(firstIdx[b * L_ + tid],  HW_ - 1);
            int s = min(secondIdx[b * L_ + tid], HW_ - 1);
            float r0 = (float)(f / W_), c0 = (float)(f % W_);
            float r1 = (float)(s / W_), c1 = (float)(s % W_);
            cd = __expf(sqrtf((r0 - c0) * (r0 - c0) + (r1 - c1) * (r1 - c1))
                        / diag * 0.5f);
            inv = 1.0f / fmaxf((float)cntf_i[b * L_ + tid], 1.0f);
        }
        sMean[tid] = mu; sCd[tid] = cd; sInv[tid] = inv;
        if (tid == 0) sAcc = 0.f;
    }
    __syncthreads();

    const int blockbase = blockIdx.x * PXB;
    const float* embb = emb + (size_t)b * D_ * HW_;
    const int o0 = blockbase + tid * 4;

    // ---- all loads up front ----
    const uint2 lp = lblpack[(size_t)(b * GRIDX + blockIdx.x) * BLOCK + tid];
    float4 E[VITER][D_];
    #pragma unroll
    for (int it = 0; it < VITER; ++it)
        #pragma unroll
        for (int d = 0; d < D_; ++d)
            E[it][d] = *(const float4*)(embb + d * HW_ + o0 + it * (BLOCK * 4));

    float acc = 0.f;
    #pragma unroll
    for (int it = 0; it < VITER; ++it) {
        const float* e0A = (const float*)&E[it][0];
        const float* e1A = (const float*)&E[it][1];
        const float* e2A = (const float*)&E[it][2];
        const float* e3A = (const float*)&E[it][3];
        #pragma unroll
        for (int c = 0; c < 4; ++c) {
            const int px = it * 4 + c;
            const int lf = (int)(((px < 8) ? (lp.x >> (4 * px))
                                           : (lp.y >> (4 * (px - 8)))) & 7u);
            const float4 mu = sMean[lf];     // 8 float4 = 32 banks: conflict-free
            float dx = e0A[c] - mu.x, dy = e1A[c] - mu.y;
            float dz = e2A[c] - mu.z, dw = e3A[c] - mu.w;
            float d2 = dx * dx + dy * dy + dz * dz + dw * dw;
            float x  = fmaxf(sCd[lf] * sqrtf(d2) - 0.5f, 0.0f);  // lf==0 -> 0
            acc += __logf(x * x + 1.0f) * sInv[lf];
        }
    }

    #pragma unroll
    for (int off = 32; off > 0; off >>= 1)
        acc += __shfl_down(acc, off);
    if ((tid & 63) == 0) atomicAdd(&sAcc, acc);
    __syncthreads();
    if (tid == 0) gatom_add(&sumvalb[b], sAcc);
}

// ---------------------------------------------------------------------------
// K4: parallel epilogue — one thread per (b, i, j) term.
// ---------------------------------------------------------------------------
__global__ __launch_bounds__(512) void k_final(
        const int* __restrict__ firstIdx, const int* __restrict__ secondIdx,
        const int* __restrict__ cntk_i, const float* __restrict__ sumemb,
        const float* __restrict__ sumvalb, float* __restrict__ out) {
    __shared__ float sWave[8];
    const int tid = threadIdx.x;
    const int b = tid >> 6, ij = tid & 63, i = ij >> 3, j = ij & 7;
    const float diag = sqrtf((float)(H_ * H_ + W_ * W_));

    float mi[D_], mj[D_];
    {
        float ci = 1.0f / fmaxf((float)cntk_i[b * L_ + i], 1.0f);
        float cj = 1.0f / fmaxf((float)cntk_i[b * L_ + j], 1.0f);
        #pragma unroll
        for (int d = 0; d < D_; ++d) {
            mi[d] = (i > 0) ? sumemb[(b * L_ + i) * D_ + d] * ci : 0.0f;
            mj[d] = (j > 0) ? sumemb[(b * L_ + j) * D_ + d] * cj : 0.0f;
        }
    }

    float contrib = 0.0f;
    if (j == 0) {            // l_reg term for label i (i=0 gives 0)
        float d2 = 0.f;
        #pragma unroll
        for (int d = 0; d < D_; ++d) d2 += mi[d] * mi[d];
        float n = (d2 > 0.f) ? sqrtf(d2) : 0.f;
        contrib += __logf(n + 1.0f) * (0.001f / (float)L_);
    }
    if (i == 0 && j == 1)    // l_agg (already /cntf per label)
        contrib += sumvalb[b] * (1.0f / (float)NL);
    if (i >= 1 && j >= 1 && i != j) {   // l_dis pair term
        float d2 = 0.f;
        #pragma unroll
        for (int d = 0; d < D_; ++d) {
            float df = mi[d] - mj[d];
            d2 += df * df;
        }
        float Dn = (d2 > 0.f) ? sqrtf(d2) : 0.f;
        int fi = min(firstIdx[b * L_ + i],  HW_ - 1);
        int si = min(secondIdx[b * L_ + i], HW_ - 1);
        int fj = min(firstIdx[b * L_ + j],  HW_ - 1);
        int sj = min(secondIdx[b * L_ + j], HW_ - 1);
        float ssi = (float)(fi / W_) + (float)(fi % W_);
        float tti = (float)(si / W_) + (float)(si % W_);
        float ssj = (float)(fj / W_) + (float)(fj % W_);
        float ttj = (float)(sj / W_) + (float)(sj % W_);
        float dx = ssi - ssj, dy = tti - ttj;
        float dp = sqrtf(dx * dx + dy * dy);
        float coef = 1.0f - 20.0f * __expf(-4.0f - 2.5f * dp / diag);
        float x = fmaxf(3.0f - coef * Dn, 0.0f);   // 2*delta_d = 3.0
        contrib += __logf(x * x + 1.0f) * (1.0f / 42.0f);
    }

    #pragma unroll
    for (int off = 32; off > 0; off >>= 1)
        contrib += __shfl_down(contrib, off);
    if ((tid & 63) == 0) sWave[tid >> 6] = contrib;
    __syncthreads();
    if (tid == 0) {
        float t = 0.f;
        #pragma unroll
        for (int w = 0; w < 8; ++w) t += sWave[w];
        out[0] = t * (1.0f / (float)B_);           // LOSS_WEIGHT = 1
    }
}

extern "C" void kernel_launch(void* const* d_in, const int* in_sizes, int n_in,
                              void* d_out, int out_size, void* d_ws, size_t ws_size,
                              hipStream_t stream) {
    const float* emb   = (const float*)d_in[0];
    const int*   inst  = (const int*)  d_in[1];
    const float* kern  = (const float*)d_in[2];
    const float* tmask = (const float*)d_in[3];
    // d_in[4] = bboxes, unused by the reference

    int*   ib        = (int*)d_ws;
    int*   firstIdx  = ib;
    int*   secondIdx = ib + 64;
    int*   cntf_i    = ib + 128;
    int*   cntk_i    = ib + 192;
    float* sumemb    = (float*)(ib + 256);
    float* sumvalb   = (float*)(ib + 512);
    uint2* lblpack   = (uint2*)(ib + 1024);
    float* out       = (float*)d_out;

    dim3 grid(GRIDX, B_);   // (100, 8) = 800 blocks

    k_init <<<1, 256, 0, stream>>>(ib);
    k_pass1<<<grid, BLOCK, 0, stream>>>(emb, inst, kern, tmask,
                                        firstIdx, secondIdx, cntf_i, cntk_i,
                                        sumemb, lblpack);
    k_pass3<<<grid, BLOCK, 0, stream>>>(emb, lblpack, firstIdx, secondIdx,
                                        cntk_i, cntf_i, sumemb, sumvalb);
    k_final<<<1, 512, 0, stream>>>(firstIdx, secondIdx, cntk_i,
                                   sumemb, sumvalb, out);
}